// Round 9
// baseline (52.935 us; speedup 1.0000x reference)
//
#include <hip/hip_runtime.h>
#include <math.h>

#define B_    16
#define N_    6
#define P_    70000
#define H_    112
#define W_    200
#define HW_   (H_ * W_)
#define BSN_  (B_ * N_)
#define QROWS  28                       // rows per slab (H_/4)
#define QCELLS (QROWS * W_)             // 5600 cells, 22.4 KB LDS
#define NSLAB  4
#define THREADS_ 1024

// ws layout: u32 arena[384 buckets][P_] | int cursors[384] | int gcorner[384]
#define NBUCKET (BSN_ * NSLAB)          // 384
#define ARENA_U32 ((size_t)NBUCKET * P_)
#define WS_NEED ((ARENA_U32 + 2 * NBUCKET) * 4)

// corner cell codes ((ym<<8)|xm): (0,0) (0,199) (111,0) (111,199)
#define CC0 0
#define CC1 199
#define CC2 28416
#define CC3 28615

// ---------- shared math helpers (identical codegen everywhere) ----------

__device__ __forceinline__ float rdot(const float r[4], float x, float y, float z) {
    float s = r[0] * x;
    s = fmaf(r[1], y, s);
    s = fmaf(r[2], z, s);
    return s + r[3];
}

__device__ __forceinline__ float rdot4(float r0, float r1, float r2, float r3,
                                       float x, float y, float z) {
    float s = r0 * x;
    s = fmaf(r1, y, s);
    s = fmaf(r2, z, s);
    return s + r3;
}

// 4x4 inverse via adjugate (matches jnp.linalg.inv bit-for-bit here — absmax
// 0.0 through rounds 1-8)
__device__ __forceinline__ void inv4(const float* m, float* o) {
    float inv[16];
    inv[0]  =  m[5]*m[10]*m[15] - m[5]*m[11]*m[14] - m[9]*m[6]*m[15] + m[9]*m[7]*m[14] + m[13]*m[6]*m[11] - m[13]*m[7]*m[10];
    inv[4]  = -m[4]*m[10]*m[15] + m[4]*m[11]*m[14] + m[8]*m[6]*m[15] - m[8]*m[7]*m[14] - m[12]*m[6]*m[11] + m[12]*m[7]*m[10];
    inv[8]  =  m[4]*m[9]*m[15]  - m[4]*m[11]*m[13] - m[8]*m[5]*m[15] + m[8]*m[7]*m[13] + m[12]*m[5]*m[11] - m[12]*m[7]*m[9];
    inv[12] = -m[4]*m[9]*m[14]  + m[4]*m[10]*m[13] + m[8]*m[5]*m[14] - m[8]*m[6]*m[13] - m[12]*m[5]*m[10] + m[12]*m[6]*m[9];
    inv[1]  = -m[1]*m[10]*m[15] + m[1]*m[11]*m[14] + m[9]*m[2]*m[15] - m[9]*m[3]*m[14] - m[13]*m[2]*m[11] + m[13]*m[3]*m[10];
    inv[5]  =  m[0]*m[10]*m[15] - m[0]*m[11]*m[14] - m[8]*m[2]*m[15] + m[8]*m[3]*m[14] + m[12]*m[2]*m[11] - m[12]*m[3]*m[10];
    inv[9]  = -m[0]*m[9]*m[15]  + m[0]*m[11]*m[13] + m[8]*m[1]*m[15] - m[8]*m[3]*m[13] - m[12]*m[1]*m[11] + m[12]*m[3]*m[9];
    inv[13] =  m[0]*m[9]*m[14]  - m[0]*m[10]*m[13] - m[8]*m[1]*m[14] + m[8]*m[2]*m[13] + m[12]*m[1]*m[10] - m[12]*m[2]*m[9];
    inv[2]  =  m[1]*m[6]*m[15]  - m[1]*m[7]*m[14]  - m[5]*m[2]*m[15] + m[5]*m[3]*m[14] + m[13]*m[2]*m[7]  - m[13]*m[3]*m[6];
    inv[6]  = -m[0]*m[6]*m[15]  + m[0]*m[7]*m[14]  + m[4]*m[2]*m[15] - m[4]*m[3]*m[14] - m[12]*m[2]*m[7]  + m[12]*m[3]*m[6];
    inv[10] =  m[0]*m[5]*m[15]  - m[0]*m[7]*m[13]  - m[4]*m[1]*m[15] + m[4]*m[3]*m[13] + m[12]*m[1]*m[7]  - m[12]*m[3]*m[5];
    inv[14] = -m[0]*m[5]*m[14]  + m[0]*m[6]*m[13]  + m[4]*m[1]*m[14] - m[4]*m[2]*m[13] - m[12]*m[1]*m[6]  + m[12]*m[2]*m[5];
    inv[3]  = -m[1]*m[6]*m[11]  + m[1]*m[7]*m[10]  + m[5]*m[2]*m[11] - m[5]*m[3]*m[10] - m[9]*m[2]*m[7]   + m[9]*m[3]*m[6];
    inv[7]  =  m[0]*m[6]*m[11]  - m[0]*m[7]*m[10]  - m[4]*m[2]*m[11] + m[4]*m[3]*m[10] + m[8]*m[2]*m[7]   - m[8]*m[3]*m[6];
    inv[11] = -m[0]*m[5]*m[11]  + m[0]*m[7]*m[9]   + m[4]*m[1]*m[11] - m[4]*m[3]*m[9]  - m[8]*m[1]*m[7]   + m[8]*m[3]*m[5];
    inv[15] =  m[0]*m[5]*m[10]  - m[0]*m[6]*m[9]   - m[4]*m[1]*m[10] + m[4]*m[2]*m[9]  + m[8]*m[1]*m[6]   - m[8]*m[2]*m[5];
    float det = m[0]*inv[0] + m[1]*inv[4] + m[2]*inv[8] + m[3]*inv[12];
    float rdet = 1.0f / det;
    for (int i = 0; i < 16; ++i) o[i] = inv[i] * rdet;
}

// Per-camera: Einv (rigid inverse) and PFC = scale_intrinsics4(K) @ Einv.
__device__ __forceinline__ void cam_mats(const float* Ein, const float* Kin,
                                         float E2[4], float PFC[3][4]) {
    float Einv[4][4];
    for (int i = 0; i < 3; ++i)
        for (int j = 0; j < 3; ++j)
            Einv[i][j] = Ein[j * 4 + i];          // R^T
    for (int i = 0; i < 3; ++i) {                  // -(R^T t), asc-j fma
        float s = Ein[0 * 4 + i] * Ein[0 * 4 + 3];
        s = fmaf(Ein[1 * 4 + i], Ein[1 * 4 + 3], s);
        s = fmaf(Ein[2 * 4 + i], Ein[2 * 4 + 3], s);
        Einv[i][3] = -s;
    }
    Einv[3][0] = Ein[12]; Einv[3][1] = Ein[13];
    Einv[3][2] = Ein[14]; Einv[3][3] = Ein[15];

    float K4[4][4] = {};
    K4[0][0] = Kin[0] * 0.25f;  K4[0][2] = Kin[2] * 0.25f;
    K4[1][1] = Kin[4] * 0.25f;  K4[1][2] = Kin[5] * 0.25f;
    K4[2][2] = 1.0f;            K4[3][3] = 1.0f;

    for (int i = 0; i < 3; ++i)
        for (int j = 0; j < 4; ++j) {
            float s = K4[i][0] * Einv[0][j];
            s = fmaf(K4[i][1], Einv[1][j], s);
            s = fmaf(K4[i][2], Einv[2][j], s);
            s = fmaf(K4[i][3], Einv[3][j], s);
            PFC[i][j] = s;
        }
    for (int j = 0; j < 4; ++j) E2[j] = Einv[2][j];
}

// ---------- K0: init cursors (0) and global corner maxima (-1) ----------

__global__ __launch_bounds__(2 * NBUCKET) void k_init_meta(int* __restrict__ meta) {
    const int t = threadIdx.x;
    meta[t] = (t < NBUCKET) ? 0 : -1;   // cursors then gcorner
}

// ---------- K1: project 6 cams, filter corners, bucket-append rest ----------
// One point per thread. Corner-coded (pt,cam) pairs (behind-camera floods)
// never enter the arena: per-wave ballot + highest-set-lane = max-p (p is
// lane-ascending), flushed via 24 LDS slots -> 24 device atomicMax per block.

#define K1CH 69                          // ceil(70000/1024)

__global__ __launch_bounds__(THREADS_) void k_bucket2(
        const float4* __restrict__ pc, const float* __restrict__ extr,
        const float* __restrict__ intr, const float* __restrict__ view,
        unsigned int* __restrict__ arena, int* __restrict__ cursors,
        int* __restrict__ gcorner) {
    __shared__ float sM[84];            // 0..11 Vinv rows, 12.. 6x12 PFC
    __shared__ int   cnt[16][24];       // per-wave per-bucket counts
    __shared__ int   wbase[16][24];     // per-wave bases
    __shared__ int   gb[24];            // per-block global bases
    __shared__ int   lc[24];            // block corner maxima (cam x 4)

    const int b    = blockIdx.x;
    const int t    = threadIdx.x;
    const int lane = t & 63;
    const int w    = t >> 6;

    if (t == 0) {                       // wave 0: Vinv
        float Vi[16];
        inv4(&view[b * 16], Vi);
        for (int k = 0; k < 12; ++k) sM[k] = Vi[k];
    } else if (t >= 64 && t < 64 + N_) {  // wave 1: 6 cameras
        int n = t - 64;
        float E2[4], PFC[3][4];
        cam_mats(&extr[(b * N_ + n) * 16], &intr[(b * N_ + n) * 9], E2, PFC);
        for (int i = 0; i < 3; ++i)
            for (int j = 0; j < 4; ++j) sM[12 + n * 12 + i * 4 + j] = PFC[i][j];
    }
    if (t >= 128 && t < 152) lc[t - 128] = -1;
    __syncthreads();

    const int p = blockIdx.y * THREADS_ + t;
    const bool valid = (p < P_);
    float4 pt = make_float4(0.f, 0.f, 0.f, 0.f);
    if (valid) pt = pc[(size_t)b * P_ + p];
    float lx = rdot(&sM[0], pt.x, pt.y, pt.z);
    float ly = rdot(&sM[4], pt.x, pt.y, pt.z);
    float lz = rdot(&sM[8], pt.x, pt.y, pt.z);

    const unsigned long long lt = (1ull << lane) - 1ull;
    const int pwbase = blockIdx.y * THREADS_ + w * 64;   // p of lane 0
    int stash[6];                        // (code<<9)|(rank<<3)|slab, or -1

    #pragma unroll
    for (int n = 0; n < 6; ++n) {
        const float* Pm = &sM[12 + n * 12];
        float px = rdot(&Pm[0], lx, ly, lz);
        float py = rdot(&Pm[4], lx, ly, lz);
        float pz = rdot(&Pm[8], lx, ly, lz);
        float denom = fmaxf(pz, 1e-6f);
        float x_ = px / denom;
        float y_ = py / denom;
        int ym = (int)fminf(fmaxf(y_, 0.0f), (float)(H_ - 1));
        int xm = (int)fminf(fmaxf(x_, 0.0f), (float)(W_ - 1));
        int code = (ym << 8) | xm;
        bool is_c = (code == CC0) | (code == CC1) | (code == CC2) | (code == CC3);
        // corner maxima via ballot + highest set lane (p lane-ascending)
        unsigned long long m0 = __ballot(valid && code == CC0);
        unsigned long long m1 = __ballot(valid && code == CC1);
        unsigned long long m2 = __ballot(valid && code == CC2);
        unsigned long long m3 = __ballot(valid && code == CC3);
        if (lane == 0) {
            if (m0) atomicMax(&lc[n * 4 + 0], pwbase + 63 - __builtin_clzll(m0));
            if (m1) atomicMax(&lc[n * 4 + 1], pwbase + 63 - __builtin_clzll(m1));
            if (m2) atomicMax(&lc[n * 4 + 2], pwbase + 63 - __builtin_clzll(m2));
            if (m3) atomicMax(&lc[n * 4 + 3], pwbase + 63 - __builtin_clzll(m3));
        }
        // slab ranking over non-corner valids
        bool act = valid && !is_c;
        int slab = (ym * 585) >> 14;     // ym/28
        unsigned long long ACT = __ballot(act);
        unsigned long long B0  = __ballot(act && (slab & 1));
        unsigned long long B1  = __ballot(act && (slab & 2));
        unsigned long long mm  = ((slab & 1) ? B0 : ~B0) &
                                 ((slab & 2) ? B1 : ~B1) & ACT;
        int rank = (int)__popcll(mm & lt);
        if (lane < 4) {
            unsigned long long ml = ((lane & 1) ? B0 : ~B0) &
                                    ((lane & 2) ? B1 : ~B1) & ACT;
            cnt[w][n * 4 + lane] = (int)__popcll(ml);
        }
        stash[n] = act ? ((code << 9) | (rank << 3) | slab) : -1;
    }
    __syncthreads();

    if (t < 24) {                        // block prefix over waves + global base
        int s = 0;
        for (int w2 = 0; w2 < 16; ++w2) { wbase[w2][t] = s; s += cnt[w2][t]; }
        gb[t] = atomicAdd(&cursors[b * 24 + t], s);
    }
    __syncthreads();

    #pragma unroll
    for (int n = 0; n < 6; ++n) {
        int sv = stash[n];
        if (sv >= 0) {
            int slab = sv & 7;
            int rank = (sv >> 3) & 63;
            int code = sv >> 9;
            int j    = n * 4 + slab;
            size_t slot = (size_t)((b * N_ + n) * NSLAB + slab) * P_ +
                          (size_t)(gb[j] + wbase[w][j] + rank);
            arena[slot] = ((unsigned int)code << 17) | (unsigned int)p;
        }
    }
    if (t < 24 && lc[t] >= 0) atomicMax(&gcorner[b * 24 + t], lc[t]);
}

// ---------- K2: dense bucket scan + finalize. Block = (b,cam,slab) ----------

__global__ __launch_bounds__(THREADS_) void k_scatfin3(
        const float4* __restrict__ pc, const unsigned int* __restrict__ arena,
        const int* __restrict__ cursors, const int* __restrict__ gcorner,
        const float* __restrict__ extr, const float* __restrict__ intr,
        const float* __restrict__ view,
        float* __restrict__ out, const int* __restrict__ bev_side_p) {
    __shared__ int   win[QCELLS];       // 22.4 KB
    __shared__ float sM[28];            // 0..11 Vinv, 12..23 PFC, 24..27 E2

    // XCD swizzle: match K1's placement (K1 block id ≡ b mod 16 -> XCD b%8)
    const int i   = blockIdx.x;
    const int xcd = i & 7;
    const int j   = i >> 3;             // 0..47
    const int b   = xcd + 8 * (j >= 24 ? 1 : 0);
    const int r   = j % 24;
    const int cam = r >> 2;
    const int q   = r & 3;
    const int m   = b * N_ + cam;
    const int rlo = q * QROWS;
    const int t   = threadIdx.x;

    if (t == 0) {                        // wave 0: Vinv
        float Vi[16];
        inv4(&view[b * 16], Vi);
        for (int k = 0; k < 12; ++k) sM[k] = Vi[k];
    } else if (t == 64) {                // wave 1: this camera
        float E2[4], PFC[3][4];
        cam_mats(&extr[m * 16], &intr[m * 9], E2, PFC);
        for (int ii = 0; ii < 3; ++ii)
            for (int jj = 0; jj < 4; ++jj) sM[12 + ii * 4 + jj] = PFC[ii][jj];
        for (int jj = 0; jj < 4; ++jj) sM[24 + jj] = E2[jj];
    }
    for (int k = t; k < QCELLS; k += THREADS_) win[k] = -1;
    __syncthreads();

    // corner injection (corner cells live in slabs 0 and 3)
    if (t == 0) {
        if (q == 0) {
            int g0 = gcorner[m * 4 + 0], g1 = gcorner[m * 4 + 1];
            if (g0 >= 0) atomicMax(&win[0],   g0);
            if (g1 >= 0) atomicMax(&win[199], g1);
        } else if (q == 3) {
            int g2 = gcorner[m * 4 + 2], g3 = gcorner[m * 4 + 3];
            if (g2 >= 0) atomicMax(&win[(H_ - 1 - rlo) * W_ + 0],   g2);
            if (g3 >= 0) atomicMax(&win[(H_ - 1 - rlo) * W_ + 199], g3);
        }
    }

    // ---- Phase A: dense scan; every entry is in-slab, non-corner ----
    const unsigned int* seg = arena + (size_t)(m * NSLAB + q) * P_;
    const int cntq = cursors[b * 24 + cam * 4 + q];
    const int nv = cntq >> 2;            // whole uint4s
    const uint4* seg4 = (const uint4*)seg;
    for (int v = t; v < nv; v += THREADS_) {
        uint4 e4 = seg4[v];
        unsigned int es[4] = {e4.x, e4.y, e4.z, e4.w};
        #pragma unroll
        for (int h = 0; h < 4; ++h) {
            unsigned int e = es[h];
            int code = (int)(e >> 17);
            int p    = (int)(e & 0x1FFFFu);
            atomicMax(&win[((code >> 8) - rlo) * W_ + (code & 255)], p);
        }
    }
    {   // scalar tail (< 4 entries)
        int k2 = (nv << 2) + t;
        if (k2 < cntq) {
            unsigned int e = seg[k2];
            int code = (int)(e >> 17);
            int p    = (int)(e & 0x1FFFFu);
            atomicMax(&win[((code >> 8) - rlo) * W_ + (code & 255)], p);
        }
    }
    __syncthreads();

    // ---- Phase B: finalize this block's rows (recompute winners only) ----
    const float bev_half = (float)bev_side_p[0] * 0.5f;   // 100.0
    const float clip_hi  = bev_half - 1.0f;               // 99.0
    const float4* pcb = pc + (size_t)b * P_;
    const int base0 = (m * 2) * HW_ + rlo * W_;
    for (int rr = t; rr < QCELLS; rr += THREADS_) {
        int wv = win[rr];
        float depth = 0.0f, iluv = 0.0f;
        if (wv >= 0) {
            float4 pt = pcb[wv];
            float lx = rdot4(sM[0],  sM[1],  sM[2],  sM[3],  pt.x, pt.y, pt.z);
            float ly = rdot4(sM[4],  sM[5],  sM[6],  sM[7],  pt.x, pt.y, pt.z);
            float lz = rdot4(sM[8],  sM[9],  sM[10], sM[11], pt.x, pt.y, pt.z);
            float z  = rdot4(sM[24], sM[25], sM[26], sM[27], lx, ly, lz);
            float px = rdot4(sM[12], sM[13], sM[14], sM[15], lx, ly, lz);
            float py = rdot4(sM[16], sM[17], sM[18], sM[19], lx, ly, lz);
            float pz = rdot4(sM[20], sM[21], sM[22], sM[23], lx, ly, lz);
            float denom = fmaxf(pz, 1e-6f);
            float x_ = px / denom;
            float y_ = py / denom;
            bool valid = (x_ > -0.5f) && (x_ < (float)W_ - 0.5f) &&
                         (y_ > -0.5f) && (y_ < (float)H_ - 0.5f) && (z > 0.0f);
            if (valid) {
                float d = fminf(fmaxf(pz, 0.0f), clip_hi);     // clip(normalizer,0,99)
                depth = d / bev_half;                           // /100
                float vi = fminf(fmaxf(pt.w, 0.0f), 255.0f);    // clip(ilu,0,255)
                iluv = log1pf(vi) / 5.545177444479562f;         // /log(256) as f32
            }
        }
        out[base0 + rr]       = depth;
        out[base0 + HW_ + rr] = iluv;
    }
}

// ---------- fallback (R8 single-kernel path, if ws too small) ----------

#define HALF_ 56
#define CELLS_ (HALF_ * W_)
#define PMAIN 69632
#define PTAIL (P_ - PMAIN)

__global__ __launch_bounds__(THREADS_, 4) void k_lidar_ilp(
        const float4* __restrict__ pc, const float* __restrict__ extr,
        const float* __restrict__ intr, const float* __restrict__ view,
        float* __restrict__ out, const int* __restrict__ bev_side_p) {
    __shared__ int   win[CELLS_];
    __shared__ float sM[28];

    const int i    = blockIdx.x;
    const int xcd  = i & 7;
    const int s    = i >> 3;
    const int b    = xcd + 8 * (s >= 12 ? 1 : 0);
    const int c12  = s % 12;
    const int m    = b * N_ + (c12 >> 1);
    const int rlo  = (c12 & 1) * HALF_;
    const int t    = threadIdx.x;

    if (t == 0) {
        float Vi[16];
        inv4(&view[b * 16], Vi);
        for (int k = 0; k < 12; ++k) sM[k] = Vi[k];
    } else if (t == 64) {
        float E2[4], PFC[3][4];
        cam_mats(&extr[m * 16], &intr[m * 9], E2, PFC);
        for (int ii = 0; ii < 3; ++ii)
            for (int jj = 0; jj < 4; ++jj) sM[12 + ii * 4 + jj] = PFC[ii][jj];
        for (int jj = 0; jj < 4; ++jj) sM[24 + jj] = E2[jj];
    }
    for (int k = t; k < CELLS_; k += THREADS_) win[k] = -1;
    __syncthreads();

    const float V0 = sM[0],  V1 = sM[1],  V2 = sM[2],  V3 = sM[3];
    const float V4 = sM[4],  V5 = sM[5],  V6 = sM[6],  V7 = sM[7];
    const float V8 = sM[8],  V9 = sM[9],  V10 = sM[10], V11 = sM[11];
    const float P00 = sM[12], P01 = sM[13], P02 = sM[14], P03 = sM[15];
    const float P10 = sM[16], P11 = sM[17], P12 = sM[18], P13 = sM[19];
    const float P20 = sM[20], P21 = sM[21], P22 = sM[22], P23 = sM[23];

    const float4* pcb = pc + (size_t)b * P_;
    int c0 = -1, c1 = -1, c2 = -1, c3 = -1;

#define PROC(PT, PIDX)                                                        \
    {                                                                         \
        float lx = rdot4(V0, V1, V2,  V3,  (PT).x, (PT).y, (PT).z);           \
        float ly = rdot4(V4, V5, V6,  V7,  (PT).x, (PT).y, (PT).z);           \
        float lz = rdot4(V8, V9, V10, V11, (PT).x, (PT).y, (PT).z);           \
        float px = rdot4(P00, P01, P02, P03, lx, ly, lz);                     \
        float py = rdot4(P10, P11, P12, P13, lx, ly, lz);                     \
        float pz = rdot4(P20, P21, P22, P23, lx, ly, lz);                     \
        float denom = fmaxf(pz, 1e-6f);                                       \
        float x_ = px / denom;                                                \
        float y_ = py / denom;                                                \
        int ym = (int)fminf(fmaxf(y_, 0.0f), (float)(H_ - 1));                \
        int xm = (int)fminf(fmaxf(x_, 0.0f), (float)(W_ - 1));                \
        bool is_c = (xm == 0 || xm == W_ - 1) && (ym == 0 || ym == H_ - 1);   \
        int code = ((ym != 0) << 1) | (xm != 0);                              \
        c0 = (is_c && code == 0) ? (PIDX) : c0;                               \
        c1 = (is_c && code == 1) ? (PIDX) : c1;                               \
        c2 = (is_c && code == 2) ? (PIDX) : c2;                               \
        c3 = (is_c && code == 3) ? (PIDX) : c3;                               \
        int rr = ym - rlo;                                                    \
        if (!is_c && (unsigned)rr < (unsigned)HALF_)                          \
            atomicMax(&win[rr * W_ + xm], (PIDX));                            \
    }

    for (int base = 0; base < PMAIN; base += 4 * THREADS_) {
        float4 q0 = pcb[base + t];
        float4 q1 = pcb[base + t + THREADS_];
        float4 q2 = pcb[base + t + 2 * THREADS_];
        float4 q3 = pcb[base + t + 3 * THREADS_];
        PROC(q0, base + t)
        PROC(q1, base + t + THREADS_)
        PROC(q2, base + t + 2 * THREADS_)
        PROC(q3, base + t + 3 * THREADS_)
    }
    if (t < PTAIL) {
        float4 q = pcb[PMAIN + t];
        PROC(q, PMAIN + t)
    }
#undef PROC

    for (int d = 32; d; d >>= 1) {
        c0 = max(c0, __shfl_xor(c0, d));
        c1 = max(c1, __shfl_xor(c1, d));
        c2 = max(c2, __shfl_xor(c2, d));
        c3 = max(c3, __shfl_xor(c3, d));
    }
    if ((t & 63) == 0) {
        if (rlo == 0) {
            if (c0 >= 0) atomicMax(&win[0],   c0);
            if (c1 >= 0) atomicMax(&win[199], c1);
        } else {
            if (c2 >= 0) atomicMax(&win[(H_ - 1 - rlo) * W_ + 0],   c2);
            if (c3 >= 0) atomicMax(&win[(H_ - 1 - rlo) * W_ + 199], c3);
        }
    }
    __syncthreads();

    const float bev_half = (float)bev_side_p[0] * 0.5f;
    const float clip_hi  = bev_half - 1.0f;
    const float E20 = sM[24], E21 = sM[25], E22 = sM[26], E23 = sM[27];
    const int base0 = (m * 2) * HW_ + rlo * W_;
    for (int r = t; r < CELLS_; r += THREADS_) {
        int w = win[r];
        float depth = 0.0f, iluv = 0.0f;
        if (w >= 0) {
            float4 pt = pcb[w];
            float lx = rdot4(V0, V1, V2,  V3,  pt.x, pt.y, pt.z);
            float ly = rdot4(V4, V5, V6,  V7,  pt.x, pt.y, pt.z);
            float lz = rdot4(V8, V9, V10, V11, pt.x, pt.y, pt.z);
            float z  = rdot4(E20, E21, E22, E23, lx, ly, lz);
            float px = rdot4(P00, P01, P02, P03, lx, ly, lz);
            float py = rdot4(P10, P11, P12, P13, lx, ly, lz);
            float pz = rdot4(P20, P21, P22, P23, lx, ly, lz);
            float denom = fmaxf(pz, 1e-6f);
            float x_ = px / denom;
            float y_ = py / denom;
            bool valid = (x_ > -0.5f) && (x_ < (float)W_ - 0.5f) &&
                         (y_ > -0.5f) && (y_ < (float)H_ - 0.5f) && (z > 0.0f);
            if (valid) {
                float d = fminf(fmaxf(pz, 0.0f), clip_hi);
                depth = d / bev_half;
                float vi = fminf(fmaxf(pt.w, 0.0f), 255.0f);
                iluv = log1pf(vi) / 5.545177444479562f;
            }
        }
        out[base0 + r]       = depth;
        out[base0 + HW_ + r] = iluv;
    }
}

// ---------- launch ----------

extern "C" void kernel_launch(void* const* d_in, const int* in_sizes, int n_in,
                              void* d_out, int out_size, void* d_ws, size_t ws_size,
                              hipStream_t stream) {
    const float4* pc  = (const float4*)d_in[0];
    const float* extr = (const float*)d_in[1];
    const float* intr = (const float*)d_in[2];
    const float* view = (const float*)d_in[3];
    const int*   bev  = (const int*)d_in[4];
    float* out = (float*)d_out;

    if (ws_size >= WS_NEED) {
        unsigned int* arena = (unsigned int*)d_ws;
        int* cursors = (int*)(arena + ARENA_U32);
        int* gcorner = cursors + NBUCKET;
        k_init_meta<<<dim3(1), dim3(2 * NBUCKET), 0, stream>>>(cursors);
        k_bucket2<<<dim3(B_, K1CH), dim3(THREADS_), 0, stream>>>(
            pc, extr, intr, view, arena, cursors, gcorner);
        k_scatfin3<<<dim3(NBUCKET), dim3(THREADS_), 0, stream>>>(
            pc, arena, cursors, gcorner, extr, intr, view, out, bev);
    } else {
        k_lidar_ilp<<<dim3(BSN_ * 2), dim3(THREADS_), 0, stream>>>(
            pc, extr, intr, view, out, bev);
    }
}

// Round 10
// 50.048 us; speedup vs baseline: 1.0577x; 1.0577x over previous
//
#include <hip/hip_runtime.h>
#include <math.h>

#define B_    16
#define N_    6
#define P_    70000
#define H_    112
#define W_    200
#define HW_   (H_ * W_)
#define BSN_  (B_ * N_)
#define QROWS  28                       // rows per slab (H_/4)
#define QCELLS (QROWS * W_)             // 5600 cells, 22.4 KB LDS
#define NSLAB  4
#define T2_   1024                      // K2 block size
#define T1_   256                       // K1 block size (4 waves)
#define K1CH  274                       // ceil(70000/256)

// ws layout: u32 arena[384 buckets][P_] | int cursors[384]
#define NBUCKET (BSN_ * NSLAB)          // 384
#define ARENA_U32 ((size_t)NBUCKET * P_)
#define WS_NEED ((ARENA_U32 + NBUCKET) * 4)

// corner cell codes ((ym<<8)|xm): (0,0) (0,199) (111,0) (111,199)
#define CC0 0
#define CC1 199
#define CC2 28416
#define CC3 28615

// ---------- shared math helpers (identical codegen everywhere) ----------

__device__ __forceinline__ float rdot(const float r[4], float x, float y, float z) {
    float s = r[0] * x;
    s = fmaf(r[1], y, s);
    s = fmaf(r[2], z, s);
    return s + r[3];
}

__device__ __forceinline__ float rdot4(float r0, float r1, float r2, float r3,
                                       float x, float y, float z) {
    float s = r0 * x;
    s = fmaf(r1, y, s);
    s = fmaf(r2, z, s);
    return s + r3;
}

// 4x4 inverse via adjugate (matches jnp.linalg.inv bit-for-bit here — absmax
// 0.0 through rounds 1-9)
__device__ __forceinline__ void inv4(const float* m, float* o) {
    float inv[16];
    inv[0]  =  m[5]*m[10]*m[15] - m[5]*m[11]*m[14] - m[9]*m[6]*m[15] + m[9]*m[7]*m[14] + m[13]*m[6]*m[11] - m[13]*m[7]*m[10];
    inv[4]  = -m[4]*m[10]*m[15] + m[4]*m[11]*m[14] + m[8]*m[6]*m[15] - m[8]*m[7]*m[14] - m[12]*m[6]*m[11] + m[12]*m[7]*m[10];
    inv[8]  =  m[4]*m[9]*m[15]  - m[4]*m[11]*m[13] - m[8]*m[5]*m[15] + m[8]*m[7]*m[13] + m[12]*m[5]*m[11] - m[12]*m[7]*m[9];
    inv[12] = -m[4]*m[9]*m[14]  + m[4]*m[10]*m[13] + m[8]*m[5]*m[14] - m[8]*m[6]*m[13] - m[12]*m[5]*m[10] + m[12]*m[6]*m[9];
    inv[1]  = -m[1]*m[10]*m[15] + m[1]*m[11]*m[14] + m[9]*m[2]*m[15] - m[9]*m[3]*m[14] - m[13]*m[2]*m[11] + m[13]*m[3]*m[10];
    inv[5]  =  m[0]*m[10]*m[15] - m[0]*m[11]*m[14] - m[8]*m[2]*m[15] + m[8]*m[3]*m[14] + m[12]*m[2]*m[11] - m[12]*m[3]*m[10];
    inv[9]  = -m[0]*m[9]*m[15]  + m[0]*m[11]*m[13] + m[8]*m[1]*m[15] - m[8]*m[3]*m[13] - m[12]*m[1]*m[11] + m[12]*m[3]*m[9];
    inv[13] =  m[0]*m[9]*m[14]  - m[0]*m[10]*m[13] - m[8]*m[1]*m[14] + m[8]*m[2]*m[13] + m[12]*m[1]*m[10] - m[12]*m[2]*m[9];
    inv[2]  =  m[1]*m[6]*m[15]  - m[1]*m[7]*m[14]  - m[5]*m[2]*m[15] + m[5]*m[3]*m[14] + m[13]*m[2]*m[7]  - m[13]*m[3]*m[6];
    inv[6]  = -m[0]*m[6]*m[15]  + m[0]*m[7]*m[14]  + m[4]*m[2]*m[15] - m[4]*m[3]*m[14] - m[12]*m[2]*m[7]  + m[12]*m[3]*m[6];
    inv[10] =  m[0]*m[5]*m[15]  - m[0]*m[7]*m[13]  - m[4]*m[1]*m[15] + m[4]*m[3]*m[13] + m[12]*m[1]*m[7]  - m[12]*m[3]*m[5];
    inv[14] = -m[0]*m[5]*m[14]  + m[0]*m[6]*m[13]  + m[4]*m[1]*m[14] - m[4]*m[2]*m[13] - m[12]*m[1]*m[6]  + m[12]*m[2]*m[5];
    inv[3]  = -m[1]*m[6]*m[11]  + m[1]*m[7]*m[10]  + m[5]*m[2]*m[11] - m[5]*m[3]*m[10] - m[9]*m[2]*m[7]   + m[9]*m[3]*m[6];
    inv[7]  =  m[0]*m[6]*m[11]  - m[0]*m[7]*m[10]  - m[4]*m[2]*m[11] + m[4]*m[3]*m[10] + m[8]*m[2]*m[7]   - m[8]*m[3]*m[6];
    inv[11] = -m[0]*m[5]*m[11]  + m[0]*m[7]*m[9]   + m[4]*m[1]*m[11] - m[4]*m[3]*m[9]  - m[8]*m[1]*m[7]   + m[8]*m[3]*m[5];
    inv[15] =  m[0]*m[5]*m[10]  - m[0]*m[6]*m[9]   - m[4]*m[1]*m[10] + m[4]*m[2]*m[9]  + m[8]*m[1]*m[6]   - m[8]*m[2]*m[5];
    float det = m[0]*inv[0] + m[1]*inv[4] + m[2]*inv[8] + m[3]*inv[12];
    float rdet = 1.0f / det;
    for (int i = 0; i < 16; ++i) o[i] = inv[i] * rdet;
}

// Per-camera: Einv (rigid inverse) and PFC = scale_intrinsics4(K) @ Einv.
__device__ __forceinline__ void cam_mats(const float* Ein, const float* Kin,
                                         float E2[4], float PFC[3][4]) {
    float Einv[4][4];
    for (int i = 0; i < 3; ++i)
        for (int j = 0; j < 3; ++j)
            Einv[i][j] = Ein[j * 4 + i];          // R^T
    for (int i = 0; i < 3; ++i) {                  // -(R^T t), asc-j fma
        float s = Ein[0 * 4 + i] * Ein[0 * 4 + 3];
        s = fmaf(Ein[1 * 4 + i], Ein[1 * 4 + 3], s);
        s = fmaf(Ein[2 * 4 + i], Ein[2 * 4 + 3], s);
        Einv[i][3] = -s;
    }
    Einv[3][0] = Ein[12]; Einv[3][1] = Ein[13];
    Einv[3][2] = Ein[14]; Einv[3][3] = Ein[15];

    float K4[4][4] = {};
    K4[0][0] = Kin[0] * 0.25f;  K4[0][2] = Kin[2] * 0.25f;
    K4[1][1] = Kin[4] * 0.25f;  K4[1][2] = Kin[5] * 0.25f;
    K4[2][2] = 1.0f;            K4[3][3] = 1.0f;

    for (int i = 0; i < 3; ++i)
        for (int j = 0; j < 4; ++j) {
            float s = K4[i][0] * Einv[0][j];
            s = fmaf(K4[i][1], Einv[1][j], s);
            s = fmaf(K4[i][2], Einv[2][j], s);
            s = fmaf(K4[i][3], Einv[3][j], s);
            PFC[i][j] = s;
        }
    for (int j = 0; j < 4; ++j) E2[j] = Einv[2][j];
}

// ---------- K0: zero the bucket cursors ----------

__global__ __launch_bounds__(NBUCKET) void k_init_cur(int* __restrict__ cursors) {
    cursors[threadIdx.x] = 0;
}

// ---------- K1: project 6 cams, append EVERY entry to its bucket ----------
// No LDS atomics, no corner special-casing. 3 ballots per cam (ACT hoisted)
// give contention-free ranks; 24 device atomicAdds per block reserve space.

__global__ __launch_bounds__(T1_) void k_bucket4(
        const float4* __restrict__ pc, const float* __restrict__ extr,
        const float* __restrict__ intr, const float* __restrict__ view,
        unsigned int* __restrict__ arena, int* __restrict__ cursors) {
    __shared__ float sM[84];            // 0..11 Vinv rows, 12.. 6x12 PFC
    __shared__ int   cnt[4][24];        // per-wave per-bucket counts
    __shared__ int   wbase[4][24];      // per-wave bases
    __shared__ int   gb[24];            // per-block global bases

    const int b    = blockIdx.x;
    const int t    = threadIdx.x;
    const int lane = t & 63;
    const int w    = t >> 6;

    if (t == 0) {                       // wave 0: Vinv
        float Vi[16];
        inv4(&view[b * 16], Vi);
        for (int k = 0; k < 12; ++k) sM[k] = Vi[k];
    } else if (t >= 64 && t < 64 + N_) {  // wave 1: 6 cameras
        int n = t - 64;
        float E2[4], PFC[3][4];
        cam_mats(&extr[(b * N_ + n) * 16], &intr[(b * N_ + n) * 9], E2, PFC);
        for (int i = 0; i < 3; ++i)
            for (int j = 0; j < 4; ++j) sM[12 + n * 12 + i * 4 + j] = PFC[i][j];
    }
    __syncthreads();

    const int p = blockIdx.y * T1_ + t;
    const bool valid = (p < P_);
    float4 pt = make_float4(0.f, 0.f, 0.f, 0.f);
    if (valid) pt = pc[(size_t)b * P_ + p];
    float lx = rdot(&sM[0], pt.x, pt.y, pt.z);
    float ly = rdot(&sM[4], pt.x, pt.y, pt.z);
    float lz = rdot(&sM[8], pt.x, pt.y, pt.z);

    const unsigned long long lt  = (1ull << lane) - 1ull;
    const unsigned long long ACT = __ballot(valid);
    int stash[6];                        // (code<<9)|(rank<<3)|slab

    #pragma unroll
    for (int n = 0; n < 6; ++n) {
        const float* Pm = &sM[12 + n * 12];
        float px = rdot(&Pm[0], lx, ly, lz);
        float py = rdot(&Pm[4], lx, ly, lz);
        float pz = rdot(&Pm[8], lx, ly, lz);
        float denom = fmaxf(pz, 1e-6f);
        float x_ = px / denom;
        float y_ = py / denom;
        int ym = (int)fminf(fmaxf(y_, 0.0f), (float)(H_ - 1));
        int xm = (int)fminf(fmaxf(x_, 0.0f), (float)(W_ - 1));
        int code = (ym << 8) | xm;
        int slab = (ym * 586) >> 14;     // floor(ym/28), exact for ym in [0,111]
        unsigned long long B0 = __ballot(valid && (slab & 1));
        unsigned long long B1 = __ballot(valid && (slab & 2));
        unsigned long long mm = ((slab & 1) ? B0 : ~B0) &
                                ((slab & 2) ? B1 : ~B1) & ACT;
        int rank = (int)__popcll(mm & lt);
        if (lane < 4) {
            unsigned long long ml = ((lane & 1) ? B0 : ~B0) &
                                    ((lane & 2) ? B1 : ~B1) & ACT;
            cnt[w][n * 4 + lane] = (int)__popcll(ml);
        }
        stash[n] = (code << 9) | (rank << 3) | slab;
    }
    __syncthreads();

    if (t < 24) {                        // prefix over 4 waves + global base
        int s = 0;
        #pragma unroll
        for (int w2 = 0; w2 < 4; ++w2) { wbase[w2][t] = s; s += cnt[w2][t]; }
        gb[t] = atomicAdd(&cursors[b * 24 + t], s);
    }
    __syncthreads();

    if (valid) {
        #pragma unroll
        for (int n = 0; n < 6; ++n) {
            int sv   = stash[n];
            int slab = sv & 7;
            int rank = (sv >> 3) & 63;
            int code = sv >> 9;
            int j    = n * 4 + slab;
            size_t slot = (size_t)(b * 24 + j) * P_ +
                          (size_t)(gb[j] + wbase[w][j] + rank);
            arena[slot] = ((unsigned int)code << 17) | (unsigned int)p;
        }
    }
}

// ---------- K2: dense bucket scan (corner register-filter) + finalize ----

__global__ __launch_bounds__(T2_) void k_scatfin4(
        const float4* __restrict__ pc, const unsigned int* __restrict__ arena,
        const int* __restrict__ cursors,
        const float* __restrict__ extr, const float* __restrict__ intr,
        const float* __restrict__ view,
        float* __restrict__ out, const int* __restrict__ bev_side_p) {
    __shared__ int   win[QCELLS];       // 22.4 KB
    __shared__ float sM[28];            // 0..11 Vinv, 12..23 PFC, 24..27 E2

    // XCD swizzle: match K1's placement (K1 blockIdx.x = b -> XCD b%8)
    const int i   = blockIdx.x;
    const int xcd = i & 7;
    const int j   = i >> 3;             // 0..47
    const int b   = xcd + 8 * (j >= 24 ? 1 : 0);
    const int r   = j % 24;
    const int cam = r >> 2;
    const int q   = r & 3;
    const int m   = b * N_ + cam;
    const int rlo = q * QROWS;
    const int t   = threadIdx.x;

    if (t == 0) {                        // wave 0: Vinv
        float Vi[16];
        inv4(&view[b * 16], Vi);
        for (int k = 0; k < 12; ++k) sM[k] = Vi[k];
    } else if (t == 64) {                // wave 1: this camera
        float E2[4], PFC[3][4];
        cam_mats(&extr[m * 16], &intr[m * 9], E2, PFC);
        for (int ii = 0; ii < 3; ++ii)
            for (int jj = 0; jj < 4; ++jj) sM[12 + ii * 4 + jj] = PFC[ii][jj];
        for (int jj = 0; jj < 4; ++jj) sM[24 + jj] = E2[jj];
    }
    for (int k = t; k < QCELLS; k += T2_) win[k] = -1;
    __syncthreads();

    // ---- Phase A: dense scan; corners kept in registers, rest -> LDS ----
    const unsigned int* seg = arena + (size_t)(b * 24 + cam * 4 + q) * P_;
    const int cntq = cursors[b * 24 + cam * 4 + q];
    const int ccA = (q == 0) ? CC0 : ((q == 3) ? CC2 : -1);
    const int ccB = (q == 0) ? CC1 : ((q == 3) ? CC3 : -1);
    int cA = -1, cB = -1;

    const int nv = cntq >> 2;            // whole uint4s
    const uint4* seg4 = (const uint4*)seg;
    for (int v = t; v < nv; v += T2_) {
        uint4 e4 = seg4[v];
        unsigned int es[4] = {e4.x, e4.y, e4.z, e4.w};
        #pragma unroll
        for (int h = 0; h < 4; ++h) {
            unsigned int e = es[h];
            int code = (int)(e >> 17);
            int p    = (int)(e & 0x1FFFFu);
            if (code == ccA)      cA = max(cA, p);
            else if (code == ccB) cB = max(cB, p);
            else {
                int rr = (code >> 8) - rlo;
                if ((unsigned)rr < (unsigned)QROWS)
                    atomicMax(&win[rr * W_ + (code & 255)], p);
            }
        }
    }
    {   // scalar tail (< 4 entries)
        int k2 = (nv << 2) + t;
        if (k2 < cntq) {
            unsigned int e = seg[k2];
            int code = (int)(e >> 17);
            int p    = (int)(e & 0x1FFFFu);
            if (code == ccA)      cA = max(cA, p);
            else if (code == ccB) cB = max(cB, p);
            else {
                int rr = (code >> 8) - rlo;
                if ((unsigned)rr < (unsigned)QROWS)
                    atomicMax(&win[rr * W_ + (code & 255)], p);
            }
        }
    }
    for (int d = 32; d; d >>= 1) {
        cA = max(cA, __shfl_xor(cA, d));
        cB = max(cB, __shfl_xor(cB, d));
    }
    if ((t & 63) == 0) {
        if (q == 0) {
            if (cA >= 0) atomicMax(&win[0],   cA);
            if (cB >= 0) atomicMax(&win[199], cB);
        } else if (q == 3) {
            if (cA >= 0) atomicMax(&win[(H_ - 1 - rlo) * W_ + 0],   cA);
            if (cB >= 0) atomicMax(&win[(H_ - 1 - rlo) * W_ + 199], cB);
        }
    }
    __syncthreads();

    // ---- Phase B: finalize this block's rows (recompute winners only) ----
    const float bev_half = (float)bev_side_p[0] * 0.5f;   // 100.0
    const float clip_hi  = bev_half - 1.0f;               // 99.0
    const float4* pcb = pc + (size_t)b * P_;
    const int base0 = (m * 2) * HW_ + rlo * W_;
    for (int rr = t; rr < QCELLS; rr += T2_) {
        int wv = win[rr];
        float depth = 0.0f, iluv = 0.0f;
        if (wv >= 0) {
            float4 pt = pcb[wv];
            float lx = rdot4(sM[0],  sM[1],  sM[2],  sM[3],  pt.x, pt.y, pt.z);
            float ly = rdot4(sM[4],  sM[5],  sM[6],  sM[7],  pt.x, pt.y, pt.z);
            float lz = rdot4(sM[8],  sM[9],  sM[10], sM[11], pt.x, pt.y, pt.z);
            float z  = rdot4(sM[24], sM[25], sM[26], sM[27], lx, ly, lz);
            float px = rdot4(sM[12], sM[13], sM[14], sM[15], lx, ly, lz);
            float py = rdot4(sM[16], sM[17], sM[18], sM[19], lx, ly, lz);
            float pz = rdot4(sM[20], sM[21], sM[22], sM[23], lx, ly, lz);
            float denom = fmaxf(pz, 1e-6f);
            float x_ = px / denom;
            float y_ = py / denom;
            bool valid = (x_ > -0.5f) && (x_ < (float)W_ - 0.5f) &&
                         (y_ > -0.5f) && (y_ < (float)H_ - 0.5f) && (z > 0.0f);
            if (valid) {
                float d = fminf(fmaxf(pz, 0.0f), clip_hi);     // clip(normalizer,0,99)
                depth = d / bev_half;                           // /100
                float vi = fminf(fmaxf(pt.w, 0.0f), 255.0f);    // clip(ilu,0,255)
                iluv = log1pf(vi) / 5.545177444479562f;         // /log(256) as f32
            }
        }
        out[base0 + rr]       = depth;
        out[base0 + HW_ + rr] = iluv;
    }
}

// ---------- fallback (R8 single-kernel path, if ws too small) ----------

#define HALF_ 56
#define CELLS_ (HALF_ * W_)
#define PMAIN 69632
#define PTAIL (P_ - PMAIN)

__global__ __launch_bounds__(T2_, 4) void k_lidar_ilp(
        const float4* __restrict__ pc, const float* __restrict__ extr,
        const float* __restrict__ intr, const float* __restrict__ view,
        float* __restrict__ out, const int* __restrict__ bev_side_p) {
    __shared__ int   win[CELLS_];
    __shared__ float sM[28];

    const int i    = blockIdx.x;
    const int xcd  = i & 7;
    const int s    = i >> 3;
    const int b    = xcd + 8 * (s >= 12 ? 1 : 0);
    const int c12  = s % 12;
    const int m    = b * N_ + (c12 >> 1);
    const int rlo  = (c12 & 1) * HALF_;
    const int t    = threadIdx.x;

    if (t == 0) {
        float Vi[16];
        inv4(&view[b * 16], Vi);
        for (int k = 0; k < 12; ++k) sM[k] = Vi[k];
    } else if (t == 64) {
        float E2[4], PFC[3][4];
        cam_mats(&extr[m * 16], &intr[m * 9], E2, PFC);
        for (int ii = 0; ii < 3; ++ii)
            for (int jj = 0; jj < 4; ++jj) sM[12 + ii * 4 + jj] = PFC[ii][jj];
        for (int jj = 0; jj < 4; ++jj) sM[24 + jj] = E2[jj];
    }
    for (int k = t; k < CELLS_; k += T2_) win[k] = -1;
    __syncthreads();

    const float V0 = sM[0],  V1 = sM[1],  V2 = sM[2],  V3 = sM[3];
    const float V4 = sM[4],  V5 = sM[5],  V6 = sM[6],  V7 = sM[7];
    const float V8 = sM[8],  V9 = sM[9],  V10 = sM[10], V11 = sM[11];
    const float P00 = sM[12], P01 = sM[13], P02 = sM[14], P03 = sM[15];
    const float P10 = sM[16], P11 = sM[17], P12 = sM[18], P13 = sM[19];
    const float P20 = sM[20], P21 = sM[21], P22 = sM[22], P23 = sM[23];

    const float4* pcb = pc + (size_t)b * P_;
    int c0 = -1, c1 = -1, c2 = -1, c3 = -1;

#define PROC(PT, PIDX)                                                        \
    {                                                                         \
        float lx = rdot4(V0, V1, V2,  V3,  (PT).x, (PT).y, (PT).z);           \
        float ly = rdot4(V4, V5, V6,  V7,  (PT).x, (PT).y, (PT).z);           \
        float lz = rdot4(V8, V9, V10, V11, (PT).x, (PT).y, (PT).z);           \
        float px = rdot4(P00, P01, P02, P03, lx, ly, lz);                     \
        float py = rdot4(P10, P11, P12, P13, lx, ly, lz);                     \
        float pz = rdot4(P20, P21, P22, P23, lx, ly, lz);                     \
        float denom = fmaxf(pz, 1e-6f);                                       \
        float x_ = px / denom;                                                \
        float y_ = py / denom;                                                \
        int ym = (int)fminf(fmaxf(y_, 0.0f), (float)(H_ - 1));                \
        int xm = (int)fminf(fmaxf(x_, 0.0f), (float)(W_ - 1));                \
        bool is_c = (xm == 0 || xm == W_ - 1) && (ym == 0 || ym == H_ - 1);   \
        int code = ((ym != 0) << 1) | (xm != 0);                              \
        c0 = (is_c && code == 0) ? (PIDX) : c0;                               \
        c1 = (is_c && code == 1) ? (PIDX) : c1;                               \
        c2 = (is_c && code == 2) ? (PIDX) : c2;                               \
        c3 = (is_c && code == 3) ? (PIDX) : c3;                               \
        int rr = ym - rlo;                                                    \
        if (!is_c && (unsigned)rr < (unsigned)HALF_)                          \
            atomicMax(&win[rr * W_ + xm], (PIDX));                            \
    }

    for (int base = 0; base < PMAIN; base += 4 * T2_) {
        float4 q0 = pcb[base + t];
        float4 q1 = pcb[base + t + T2_];
        float4 q2 = pcb[base + t + 2 * T2_];
        float4 q3 = pcb[base + t + 3 * T2_];
        PROC(q0, base + t)
        PROC(q1, base + t + T2_)
        PROC(q2, base + t + 2 * T2_)
        PROC(q3, base + t + 3 * T2_)
    }
    if (t < PTAIL) {
        float4 q = pcb[PMAIN + t];
        PROC(q, PMAIN + t)
    }
#undef PROC

    for (int d = 32; d; d >>= 1) {
        c0 = max(c0, __shfl_xor(c0, d));
        c1 = max(c1, __shfl_xor(c1, d));
        c2 = max(c2, __shfl_xor(c2, d));
        c3 = max(c3, __shfl_xor(c3, d));
    }
    if ((t & 63) == 0) {
        if (rlo == 0) {
            if (c0 >= 0) atomicMax(&win[0],   c0);
            if (c1 >= 0) atomicMax(&win[199], c1);
        } else {
            if (c2 >= 0) atomicMax(&win[(H_ - 1 - rlo) * W_ + 0],   c2);
            if (c3 >= 0) atomicMax(&win[(H_ - 1 - rlo) * W_ + 199], c3);
        }
    }
    __syncthreads();

    const float bev_half = (float)bev_side_p[0] * 0.5f;
    const float clip_hi  = bev_half - 1.0f;
    const float E20 = sM[24], E21 = sM[25], E22 = sM[26], E23 = sM[27];
    const int base0 = (m * 2) * HW_ + rlo * W_;
    for (int r = t; r < CELLS_; r += T2_) {
        int w = win[r];
        float depth = 0.0f, iluv = 0.0f;
        if (w >= 0) {
            float4 pt = pcb[w];
            float lx = rdot4(V0, V1, V2,  V3,  pt.x, pt.y, pt.z);
            float ly = rdot4(V4, V5, V6,  V7,  pt.x, pt.y, pt.z);
            float lz = rdot4(V8, V9, V10, V11, pt.x, pt.y, pt.z);
            float z  = rdot4(E20, E21, E22, E23, lx, ly, lz);
            float px = rdot4(P00, P01, P02, P03, lx, ly, lz);
            float py = rdot4(P10, P11, P12, P13, lx, ly, lz);
            float pz = rdot4(P20, P21, P22, P23, lx, ly, lz);
            float denom = fmaxf(pz, 1e-6f);
            float x_ = px / denom;
            float y_ = py / denom;
            bool valid = (x_ > -0.5f) && (x_ < (float)W_ - 0.5f) &&
                         (y_ > -0.5f) && (y_ < (float)H_ - 0.5f) && (z > 0.0f);
            if (valid) {
                float d = fminf(fmaxf(pz, 0.0f), clip_hi);
                depth = d / bev_half;
                float vi = fminf(fmaxf(pt.w, 0.0f), 255.0f);
                iluv = log1pf(vi) / 5.545177444479562f;
            }
        }
        out[base0 + r]       = depth;
        out[base0 + HW_ + r] = iluv;
    }
}

// ---------- launch ----------

extern "C" void kernel_launch(void* const* d_in, const int* in_sizes, int n_in,
                              void* d_out, int out_size, void* d_ws, size_t ws_size,
                              hipStream_t stream) {
    const float4* pc  = (const float4*)d_in[0];
    const float* extr = (const float*)d_in[1];
    const float* intr = (const float*)d_in[2];
    const float* view = (const float*)d_in[3];
    const int*   bev  = (const int*)d_in[4];
    float* out = (float*)d_out;

    if (ws_size >= WS_NEED) {
        unsigned int* arena = (unsigned int*)d_ws;
        int* cursors = (int*)(arena + ARENA_U32);
        k_init_cur<<<dim3(1), dim3(NBUCKET), 0, stream>>>(cursors);
        k_bucket4<<<dim3(B_, K1CH), dim3(T1_), 0, stream>>>(
            pc, extr, intr, view, arena, cursors);
        k_scatfin4<<<dim3(NBUCKET), dim3(T2_), 0, stream>>>(
            pc, arena, cursors, extr, intr, view, out, bev);
    } else {
        k_lidar_ilp<<<dim3(BSN_ * 2), dim3(T2_), 0, stream>>>(
            pc, extr, intr, view, out, bev);
    }
}

// Round 11
// 48.560 us; speedup vs baseline: 1.0901x; 1.0306x over previous
//
#include <hip/hip_runtime.h>
#include <math.h>

#define B_    16
#define N_    6
#define P_    70000
#define H_    112
#define W_    200
#define HW_   (H_ * W_)
#define BSN_  (B_ * N_)
#define HALF_ 56                       // rows per half-grid
#define CELLS_ (HALF_ * W_)            // 11200 cells, 44.8 KB LDS
#define NSEG  4
#define SEGPTS (P_ / NSEG)             // 17500
#define T1_   512                      // k_partial threads (8 waves)
#define T2_   1024                     // k_mergefin threads

// ws: int partial[96][2][NSEG][CELLS_]  = 34.4 MB, fully written by K1
#define WS_NEED ((size_t)BSN_ * 2 * NSEG * CELLS_ * 4)

// ---------- shared math helpers (identical codegen everywhere) ----------

__device__ __forceinline__ float rdot4(float r0, float r1, float r2, float r3,
                                       float x, float y, float z) {
    float s = r0 * x;
    s = fmaf(r1, y, s);
    s = fmaf(r2, z, s);
    return s + r3;
}

// 4x4 inverse via adjugate (matches jnp.linalg.inv bit-for-bit here — absmax
// 0.0 through rounds 1-10)
__device__ __forceinline__ void inv4(const float* m, float* o) {
    float inv[16];
    inv[0]  =  m[5]*m[10]*m[15] - m[5]*m[11]*m[14] - m[9]*m[6]*m[15] + m[9]*m[7]*m[14] + m[13]*m[6]*m[11] - m[13]*m[7]*m[10];
    inv[4]  = -m[4]*m[10]*m[15] + m[4]*m[11]*m[14] + m[8]*m[6]*m[15] - m[8]*m[7]*m[14] - m[12]*m[6]*m[11] + m[12]*m[7]*m[10];
    inv[8]  =  m[4]*m[9]*m[15]  - m[4]*m[11]*m[13] - m[8]*m[5]*m[15] + m[8]*m[7]*m[13] + m[12]*m[5]*m[11] - m[12]*m[7]*m[9];
    inv[12] = -m[4]*m[9]*m[14]  + m[4]*m[10]*m[13] + m[8]*m[5]*m[14] - m[8]*m[6]*m[13] - m[12]*m[5]*m[10] + m[12]*m[6]*m[9];
    inv[1]  = -m[1]*m[10]*m[15] + m[1]*m[11]*m[14] + m[9]*m[2]*m[15] - m[9]*m[3]*m[14] - m[13]*m[2]*m[11] + m[13]*m[3]*m[10];
    inv[5]  =  m[0]*m[10]*m[15] - m[0]*m[11]*m[14] - m[8]*m[2]*m[15] + m[8]*m[3]*m[14] + m[12]*m[2]*m[11] - m[12]*m[3]*m[10];
    inv[9]  = -m[0]*m[9]*m[15]  + m[0]*m[11]*m[13] + m[8]*m[1]*m[15] - m[8]*m[3]*m[13] - m[12]*m[1]*m[11] + m[12]*m[3]*m[9];
    inv[13] =  m[0]*m[9]*m[14]  - m[0]*m[10]*m[13] - m[8]*m[1]*m[14] + m[8]*m[2]*m[13] + m[12]*m[1]*m[10] - m[12]*m[2]*m[9];
    inv[2]  =  m[1]*m[6]*m[15]  - m[1]*m[7]*m[14]  - m[5]*m[2]*m[15] + m[5]*m[3]*m[14] + m[13]*m[2]*m[7]  - m[13]*m[3]*m[6];
    inv[6]  = -m[0]*m[6]*m[15]  + m[0]*m[7]*m[14]  + m[4]*m[2]*m[15] - m[4]*m[3]*m[14] - m[12]*m[2]*m[7]  + m[12]*m[3]*m[6];
    inv[10] =  m[0]*m[5]*m[15]  - m[0]*m[7]*m[13]  - m[4]*m[1]*m[15] + m[4]*m[3]*m[13] + m[12]*m[1]*m[7]  - m[12]*m[3]*m[5];
    inv[14] = -m[0]*m[5]*m[14]  + m[0]*m[6]*m[13]  + m[4]*m[1]*m[14] - m[4]*m[2]*m[13] - m[12]*m[1]*m[6]  + m[12]*m[2]*m[5];
    inv[3]  = -m[1]*m[6]*m[11]  + m[1]*m[7]*m[10]  + m[5]*m[2]*m[11] - m[5]*m[3]*m[10] - m[9]*m[2]*m[7]   + m[9]*m[3]*m[6];
    inv[7]  =  m[0]*m[6]*m[11]  - m[0]*m[7]*m[10]  - m[4]*m[2]*m[11] + m[4]*m[3]*m[10] + m[8]*m[2]*m[7]   - m[8]*m[3]*m[6];
    inv[11] = -m[0]*m[5]*m[11]  + m[0]*m[7]*m[9]   + m[4]*m[1]*m[11] - m[4]*m[3]*m[9]  - m[8]*m[1]*m[7]   + m[8]*m[3]*m[5];
    inv[15] =  m[0]*m[5]*m[10]  - m[0]*m[6]*m[9]   - m[4]*m[1]*m[10] + m[4]*m[2]*m[9]  + m[8]*m[1]*m[6]   - m[8]*m[2]*m[5];
    float det = m[0]*inv[0] + m[1]*inv[4] + m[2]*inv[8] + m[3]*inv[12];
    float rdet = 1.0f / det;
    for (int i = 0; i < 16; ++i) o[i] = inv[i] * rdet;
}

// Per-camera: Einv (rigid inverse) and PFC = scale_intrinsics4(K) @ Einv.
__device__ __forceinline__ void cam_mats(const float* Ein, const float* Kin,
                                         float E2[4], float PFC[3][4]) {
    float Einv[4][4];
    for (int i = 0; i < 3; ++i)
        for (int j = 0; j < 3; ++j)
            Einv[i][j] = Ein[j * 4 + i];          // R^T
    for (int i = 0; i < 3; ++i) {                  // -(R^T t), asc-j fma
        float s = Ein[0 * 4 + i] * Ein[0 * 4 + 3];
        s = fmaf(Ein[1 * 4 + i], Ein[1 * 4 + 3], s);
        s = fmaf(Ein[2 * 4 + i], Ein[2 * 4 + 3], s);
        Einv[i][3] = -s;
    }
    Einv[3][0] = Ein[12]; Einv[3][1] = Ein[13];
    Einv[3][2] = Ein[14]; Einv[3][3] = Ein[15];

    float K4[4][4] = {};
    K4[0][0] = Kin[0] * 0.25f;  K4[0][2] = Kin[2] * 0.25f;
    K4[1][1] = Kin[4] * 0.25f;  K4[1][2] = Kin[5] * 0.25f;
    K4[2][2] = 1.0f;            K4[3][3] = 1.0f;

    for (int i = 0; i < 3; ++i)
        for (int j = 0; j < 4; ++j) {
            float s = K4[i][0] * Einv[0][j];
            s = fmaf(K4[i][1], Einv[1][j], s);
            s = fmaf(K4[i][2], Einv[2][j], s);
            s = fmaf(K4[i][3], Einv[3][j], s);
            PFC[i][j] = s;
        }
    for (int j = 0; j < 4; ++j) E2[j] = Einv[2][j];
}

// ---------- K1: partial winner grids. Block = (cam, half, seg) ----------
// 768 blocks x 512 threads, 44.9 KB LDS -> exactly 3 blocks/CU (24 waves),
// all co-resident and balanced. Each block scans 17500 points into its own
// LDS half-grid (corner cells register-cached), then dumps the grid to ws
// with plain coalesced stores. No device atomics anywhere.

__global__ __launch_bounds__(T1_) void k_partial(
        const float4* __restrict__ pc, const float* __restrict__ extr,
        const float* __restrict__ intr, const float* __restrict__ view,
        int* __restrict__ partial) {
    __shared__ int   win[CELLS_];      // 44.8 KB
    __shared__ float sM[24];           // 0..11 Vinv, 12..23 PFC

    // XCD swizzle: 768 blocks, 96/XCD = 2 batches' worth (48 blocks/batch)
    const int i    = blockIdx.x;
    const int xcd  = i & 7;
    const int j    = i >> 3;           // 0..95
    const int b    = xcd + 8 * (j >= 48 ? 1 : 0);
    const int r    = j % 48;
    const int cam  = r >> 3;           // /8 (2 half x 4 seg)
    const int half = (r >> 2) & 1;
    const int seg  = r & 3;
    const int m    = b * N_ + cam;
    const int rlo  = half * HALF_;
    const int t    = threadIdx.x;

    if (t == 0) {                      // wave 0: Vinv
        float Vi[16];
        inv4(&view[b * 16], Vi);
        for (int k = 0; k < 12; ++k) sM[k] = Vi[k];
    } else if (t == 64) {              // wave 1: this camera's PFC
        float E2[4], PFC[3][4];
        cam_mats(&extr[m * 16], &intr[m * 9], E2, PFC);
        for (int ii = 0; ii < 3; ++ii)
            for (int jj = 0; jj < 4; ++jj) sM[12 + ii * 4 + jj] = PFC[ii][jj];
    }
    for (int k = t; k < CELLS_; k += T1_) win[k] = -1;
    __syncthreads();

    const float V0 = sM[0],  V1 = sM[1],  V2 = sM[2],  V3 = sM[3];
    const float V4 = sM[4],  V5 = sM[5],  V6 = sM[6],  V7 = sM[7];
    const float V8 = sM[8],  V9 = sM[9],  V10 = sM[10], V11 = sM[11];
    const float P00 = sM[12], P01 = sM[13], P02 = sM[14], P03 = sM[15];
    const float P10 = sM[16], P11 = sM[17], P12 = sM[18], P13 = sM[19];
    const float P20 = sM[20], P21 = sM[21], P22 = sM[22], P23 = sM[23];

    const float4* pcb = pc + (size_t)b * P_;
    int c0 = -1, c1 = -1, c2 = -1, c3 = -1;
    const int p0 = seg * SEGPTS;

    for (int p = p0 + t; p < p0 + SEGPTS; p += T1_) {   // p ascending/thread
        float4 pt = pcb[p];
        float lx = rdot4(V0, V1, V2,  V3,  pt.x, pt.y, pt.z);
        float ly = rdot4(V4, V5, V6,  V7,  pt.x, pt.y, pt.z);
        float lz = rdot4(V8, V9, V10, V11, pt.x, pt.y, pt.z);
        float px = rdot4(P00, P01, P02, P03, lx, ly, lz);
        float py = rdot4(P10, P11, P12, P13, lx, ly, lz);
        float pz = rdot4(P20, P21, P22, P23, lx, ly, lz);
        float denom = fmaxf(pz, 1e-6f);
        float x_ = px / denom;
        float y_ = py / denom;
        int ym = (int)fminf(fmaxf(y_, 0.0f), (float)(H_ - 1));
        int xm = (int)fminf(fmaxf(x_, 0.0f), (float)(W_ - 1));
        bool is_c = (xm == 0 || xm == W_ - 1) && (ym == 0 || ym == H_ - 1);
        int code = ((ym != 0) << 1) | (xm != 0);
        c0 = (is_c && code == 0) ? p : c0;
        c1 = (is_c && code == 1) ? p : c1;
        c2 = (is_c && code == 2) ? p : c2;
        c3 = (is_c && code == 3) ? p : c3;
        int rr = ym - rlo;
        if (!is_c && (unsigned)rr < (unsigned)HALF_)
            atomicMax(&win[rr * W_ + xm], p);
    }
    // wave-reduce corner maxima, one LDS atomic per wave per in-half corner
    for (int d = 32; d; d >>= 1) {
        c0 = max(c0, __shfl_xor(c0, d));
        c1 = max(c1, __shfl_xor(c1, d));
        c2 = max(c2, __shfl_xor(c2, d));
        c3 = max(c3, __shfl_xor(c3, d));
    }
    if ((t & 63) == 0) {
        if (half == 0) {
            if (c0 >= 0) atomicMax(&win[0],   c0);
            if (c1 >= 0) atomicMax(&win[199], c1);
        } else {
            if (c2 >= 0) atomicMax(&win[(H_ - 1 - rlo) * W_ + 0],   c2);
            if (c3 >= 0) atomicMax(&win[(H_ - 1 - rlo) * W_ + 199], c3);
        }
    }
    __syncthreads();

    // dump partial grid (plain coalesced stores)
    int* dst = partial + (size_t)(((m * 2 + half) * NSEG) + seg) * CELLS_;
    for (int k = t; k < CELLS_; k += T1_) dst[k] = win[k];
}

// ---------- K2: merge 4 partials + finalize. Block = (cam, half) ----------

__global__ __launch_bounds__(T2_) void k_mergefin(
        const float4* __restrict__ pc, const int* __restrict__ partial,
        const float* __restrict__ extr, const float* __restrict__ intr,
        const float* __restrict__ view,
        float* __restrict__ out, const int* __restrict__ bev_side_p) {
    __shared__ float sM[28];           // 0..11 Vinv, 12..23 PFC, 24..27 E2

    const int i    = blockIdx.x;
    const int xcd  = i & 7;
    const int j    = i >> 3;           // 0..23
    const int b    = xcd + 8 * (j >= 12 ? 1 : 0);
    const int r    = j % 12;
    const int cam  = r >> 1;
    const int half = r & 1;
    const int m    = b * N_ + cam;
    const int rlo  = half * HALF_;
    const int t    = threadIdx.x;

    if (t == 0) {
        float Vi[16];
        inv4(&view[b * 16], Vi);
        for (int k = 0; k < 12; ++k) sM[k] = Vi[k];
    } else if (t == 64) {
        float E2[4], PFC[3][4];
        cam_mats(&extr[m * 16], &intr[m * 9], E2, PFC);
        for (int ii = 0; ii < 3; ++ii)
            for (int jj = 0; jj < 4; ++jj) sM[12 + ii * 4 + jj] = PFC[ii][jj];
        for (int jj = 0; jj < 4; ++jj) sM[24 + jj] = E2[jj];
    }
    __syncthreads();

    const float bev_half = (float)bev_side_p[0] * 0.5f;   // 100.0
    const float clip_hi  = bev_half - 1.0f;               // 99.0
    const float4* pcb = pc + (size_t)b * P_;
    const int* pp = partial + (size_t)((m * 2 + half) * NSEG) * CELLS_;
    const int base0 = (m * 2) * HW_ + rlo * W_;

    for (int rr = t; rr < CELLS_; rr += T2_) {
        int wv = max(max(pp[rr], pp[CELLS_ + rr]),
                     max(pp[2 * CELLS_ + rr], pp[3 * CELLS_ + rr]));
        float depth = 0.0f, iluv = 0.0f;
        if (wv >= 0) {
            float4 pt = pcb[wv];
            float lx = rdot4(sM[0],  sM[1],  sM[2],  sM[3],  pt.x, pt.y, pt.z);
            float ly = rdot4(sM[4],  sM[5],  sM[6],  sM[7],  pt.x, pt.y, pt.z);
            float lz = rdot4(sM[8],  sM[9],  sM[10], sM[11], pt.x, pt.y, pt.z);
            float z  = rdot4(sM[24], sM[25], sM[26], sM[27], lx, ly, lz);
            float px = rdot4(sM[12], sM[13], sM[14], sM[15], lx, ly, lz);
            float py = rdot4(sM[16], sM[17], sM[18], sM[19], lx, ly, lz);
            float pz = rdot4(sM[20], sM[21], sM[22], sM[23], lx, ly, lz);
            float denom = fmaxf(pz, 1e-6f);
            float x_ = px / denom;
            float y_ = py / denom;
            bool valid = (x_ > -0.5f) && (x_ < (float)W_ - 0.5f) &&
                         (y_ > -0.5f) && (y_ < (float)H_ - 0.5f) && (z > 0.0f);
            if (valid) {
                float d = fminf(fmaxf(pz, 0.0f), clip_hi);     // clip(normalizer,0,99)
                depth = d / bev_half;                           // /100
                float vi = fminf(fmaxf(pt.w, 0.0f), 255.0f);    // clip(ilu,0,255)
                iluv = log1pf(vi) / 5.545177444479562f;         // /log(256) as f32
            }
        }
        out[base0 + rr]       = depth;
        out[base0 + HW_ + rr] = iluv;
    }
}

// ---------- fallback (R8 single-kernel path, if ws too small) ----------

#define PMAIN 69632
#define PTAIL (P_ - PMAIN)

__global__ __launch_bounds__(1024, 4) void k_lidar_ilp(
        const float4* __restrict__ pc, const float* __restrict__ extr,
        const float* __restrict__ intr, const float* __restrict__ view,
        float* __restrict__ out, const int* __restrict__ bev_side_p) {
    __shared__ int   win[CELLS_];
    __shared__ float sM[28];

    const int i    = blockIdx.x;
    const int xcd  = i & 7;
    const int s    = i >> 3;
    const int b    = xcd + 8 * (s >= 12 ? 1 : 0);
    const int c12  = s % 12;
    const int m    = b * N_ + (c12 >> 1);
    const int rlo  = (c12 & 1) * HALF_;
    const int t    = threadIdx.x;

    if (t == 0) {
        float Vi[16];
        inv4(&view[b * 16], Vi);
        for (int k = 0; k < 12; ++k) sM[k] = Vi[k];
    } else if (t == 64) {
        float E2[4], PFC[3][4];
        cam_mats(&extr[m * 16], &intr[m * 9], E2, PFC);
        for (int ii = 0; ii < 3; ++ii)
            for (int jj = 0; jj < 4; ++jj) sM[12 + ii * 4 + jj] = PFC[ii][jj];
        for (int jj = 0; jj < 4; ++jj) sM[24 + jj] = E2[jj];
    }
    for (int k = t; k < CELLS_; k += 1024) win[k] = -1;
    __syncthreads();

    const float V0 = sM[0],  V1 = sM[1],  V2 = sM[2],  V3 = sM[3];
    const float V4 = sM[4],  V5 = sM[5],  V6 = sM[6],  V7 = sM[7];
    const float V8 = sM[8],  V9 = sM[9],  V10 = sM[10], V11 = sM[11];
    const float P00 = sM[12], P01 = sM[13], P02 = sM[14], P03 = sM[15];
    const float P10 = sM[16], P11 = sM[17], P12 = sM[18], P13 = sM[19];
    const float P20 = sM[20], P21 = sM[21], P22 = sM[22], P23 = sM[23];

    const float4* pcb = pc + (size_t)b * P_;
    int c0 = -1, c1 = -1, c2 = -1, c3 = -1;

#define PROC(PT, PIDX)                                                        \
    {                                                                         \
        float lx = rdot4(V0, V1, V2,  V3,  (PT).x, (PT).y, (PT).z);           \
        float ly = rdot4(V4, V5, V6,  V7,  (PT).x, (PT).y, (PT).z);           \
        float lz = rdot4(V8, V9, V10, V11, (PT).x, (PT).y, (PT).z);           \
        float px = rdot4(P00, P01, P02, P03, lx, ly, lz);                     \
        float py = rdot4(P10, P11, P12, P13, lx, ly, lz);                     \
        float pz = rdot4(P20, P21, P22, P23, lx, ly, lz);                     \
        float denom = fmaxf(pz, 1e-6f);                                       \
        float x_ = px / denom;                                                \
        float y_ = py / denom;                                                \
        int ym = (int)fminf(fmaxf(y_, 0.0f), (float)(H_ - 1));                \
        int xm = (int)fminf(fmaxf(x_, 0.0f), (float)(W_ - 1));                \
        bool is_c = (xm == 0 || xm == W_ - 1) && (ym == 0 || ym == H_ - 1);   \
        int code = ((ym != 0) << 1) | (xm != 0);                              \
        c0 = (is_c && code == 0) ? (PIDX) : c0;                               \
        c1 = (is_c && code == 1) ? (PIDX) : c1;                               \
        c2 = (is_c && code == 2) ? (PIDX) : c2;                               \
        c3 = (is_c && code == 3) ? (PIDX) : c3;                               \
        int rr = ym - rlo;                                                    \
        if (!is_c && (unsigned)rr < (unsigned)HALF_)                          \
            atomicMax(&win[rr * W_ + xm], (PIDX));                            \
    }

    for (int base = 0; base < PMAIN; base += 4 * 1024) {
        float4 q0 = pcb[base + t];
        float4 q1 = pcb[base + t + 1024];
        float4 q2 = pcb[base + t + 2 * 1024];
        float4 q3 = pcb[base + t + 3 * 1024];
        PROC(q0, base + t)
        PROC(q1, base + t + 1024)
        PROC(q2, base + t + 2 * 1024)
        PROC(q3, base + t + 3 * 1024)
    }
    if (t < PTAIL) {
        float4 q = pcb[PMAIN + t];
        PROC(q, PMAIN + t)
    }
#undef PROC

    for (int d = 32; d; d >>= 1) {
        c0 = max(c0, __shfl_xor(c0, d));
        c1 = max(c1, __shfl_xor(c1, d));
        c2 = max(c2, __shfl_xor(c2, d));
        c3 = max(c3, __shfl_xor(c3, d));
    }
    if ((t & 63) == 0) {
        if (rlo == 0) {
            if (c0 >= 0) atomicMax(&win[0],   c0);
            if (c1 >= 0) atomicMax(&win[199], c1);
        } else {
            if (c2 >= 0) atomicMax(&win[(H_ - 1 - rlo) * W_ + 0],   c2);
            if (c3 >= 0) atomicMax(&win[(H_ - 1 - rlo) * W_ + 199], c3);
        }
    }
    __syncthreads();

    const float bev_half = (float)bev_side_p[0] * 0.5f;
    const float clip_hi  = bev_half - 1.0f;
    const float E20 = sM[24], E21 = sM[25], E22 = sM[26], E23 = sM[27];
    const int base0 = (m * 2) * HW_ + rlo * W_;
    for (int r = t; r < CELLS_; r += 1024) {
        int w = win[r];
        float depth = 0.0f, iluv = 0.0f;
        if (w >= 0) {
            float4 pt = pcb[w];
            float lx = rdot4(V0, V1, V2,  V3,  pt.x, pt.y, pt.z);
            float ly = rdot4(V4, V5, V6,  V7,  pt.x, pt.y, pt.z);
            float lz = rdot4(V8, V9, V10, V11, pt.x, pt.y, pt.z);
            float z  = rdot4(E20, E21, E22, E23, lx, ly, lz);
            float px = rdot4(P00, P01, P02, P03, lx, ly, lz);
            float py = rdot4(P10, P11, P12, P13, lx, ly, lz);
            float pz = rdot4(P20, P21, P22, P23, lx, ly, lz);
            float denom = fmaxf(pz, 1e-6f);
            float x_ = px / denom;
            float y_ = py / denom;
            bool valid = (x_ > -0.5f) && (x_ < (float)W_ - 0.5f) &&
                         (y_ > -0.5f) && (y_ < (float)H_ - 0.5f) && (z > 0.0f);
            if (valid) {
                float d = fminf(fmaxf(pz, 0.0f), clip_hi);
                depth = d / bev_half;
                float vi = fminf(fmaxf(pt.w, 0.0f), 255.0f);
                iluv = log1pf(vi) / 5.545177444479562f;
            }
        }
        out[base0 + r]       = depth;
        out[base0 + HW_ + r] = iluv;
    }
}

// ---------- launch ----------

extern "C" void kernel_launch(void* const* d_in, const int* in_sizes, int n_in,
                              void* d_out, int out_size, void* d_ws, size_t ws_size,
                              hipStream_t stream) {
    const float4* pc  = (const float4*)d_in[0];
    const float* extr = (const float*)d_in[1];
    const float* intr = (const float*)d_in[2];
    const float* view = (const float*)d_in[3];
    const int*   bev  = (const int*)d_in[4];
    float* out = (float*)d_out;

    if (ws_size >= WS_NEED) {
        int* partial = (int*)d_ws;
        k_partial<<<dim3(BSN_ * 2 * NSEG), dim3(T1_), 0, stream>>>(
            pc, extr, intr, view, partial);
        k_mergefin<<<dim3(BSN_ * 2), dim3(T2_), 0, stream>>>(
            pc, partial, extr, intr, view, out, bev);
    } else {
        k_lidar_ilp<<<dim3(BSN_ * 2), dim3(1024), 0, stream>>>(
            pc, extr, intr, view, out, bev);
    }
}